// Round 3
// baseline (1289.447 us; speedup 1.0000x reference)
//
#include <hip/hip_runtime.h>
#include <hip/hip_bf16.h>
#include <stdint.h>

#define N 4096
#define LSTEPS 128
#define KSEL 16
#define NACT 3968
#define NIN 128

typedef __hip_bfloat16 bf16;
typedef __attribute__((ext_vector_type(8))) short short8;
typedef __attribute__((ext_vector_type(4))) float floatx4;

static __device__ __forceinline__ bf16 f2bf(float x) { return __float2bfloat16(x); }
static __device__ __forceinline__ float us2f(ushort u) { return __uint_as_float(((unsigned)u) << 16); }
static __device__ __forceinline__ ushort f2us(float x) { return __bfloat16_as_ushort(__float2bfloat16(x)); }

// ---------------------------------------------------------------------------
// K1: right-scan. Column-separable: block b owns columns [4b, 4b+4) of R in a
// 64KB LDS slab (fp32) and applies all 128 steps sequentially. Writes
// Rt16 = R^T in bf16 (coalesced rows). Os is fp32.
// ---------------------------------------------------------------------------
__global__ __launch_bounds__(64) void rscan_kernel(const float* __restrict__ Os,
                                                   const int* __restrict__ sel,
                                                   bf16* __restrict__ Rt16) {
    __shared__ float slab[N * 4];  // slab[row*4 + cc] = R[row][c0+cc]
    const int t = threadIdx.x;
    const int cc = t & 3;
    const int a = t >> 2;
    const int c0 = blockIdx.x * 4;

    for (int r = t; r < N * 4; r += 64) slab[r] = 0.0f;
    __syncthreads();
    if (t < 4) slab[(c0 + t) * 4 + t] = 1.0f;
    __syncthreads();

    int selr[16];
    float orow[16];
#pragma unroll
    for (int i = 0; i < 16; i++) selr[i] = sel[i];
#pragma unroll
    for (int i = 0; i < 16; i++) orow[i] = Os[a * 16 + i];

    for (int l = 0; l < LSTEPS; l++) {
        float v = 0.0f;
#pragma unroll
        for (int i = 0; i < 16; i++) v += orow[i] * slab[selr[i] * 4 + cc];
        const int wrow = selr[a];
        int seln[16] = {0};
        float orown[16] = {0.f};
        if (l + 1 < LSTEPS) {
#pragma unroll
            for (int i = 0; i < 16; i++) seln[i] = sel[(l + 1) * 16 + i];
#pragma unroll
            for (int i = 0; i < 16; i++) orown[i] = Os[(l + 1) * 256 + a * 16 + i];
        }
        __syncthreads();
        slab[wrow * 4 + cc] = v;
        __syncthreads();
#pragma unroll
        for (int i = 0; i < 16; i++) { selr[i] = seln[i]; orow[i] = orown[i]; }
    }

    // write out R^T rows (coalesced): Rt16[c][r] = R[r][c]
    for (int ccw = 0; ccw < 4; ccw++) {
        bf16* dst = Rt16 + (size_t)(c0 + ccw) * N;
        for (int r = t; r < N; r += 64) dst[r] = f2bf(slab[r * 4 + ccw]);
    }
}

// ---------------------------------------------------------------------------
// K2: flags/ranks via binary search over the sorted index lists.
// ---------------------------------------------------------------------------
__global__ void prep_kernel(const int* __restrict__ act, const int* __restrict__ inact,
                            int* __restrict__ flags, int* __restrict__ rank) {
    int i = blockIdx.x * blockDim.x + threadIdx.x;
    if (i >= N) return;
    int lo = 0, hi = NACT - 1, f = 0, r = -1;
    while (lo <= hi) {
        int mid = (lo + hi) >> 1, v = act[mid];
        if (v == i) { f = 1; r = mid; break; }
        if (v < i) lo = mid + 1; else hi = mid - 1;
    }
    if (!f) {
        lo = 0; hi = NIN - 1;
        while (lo <= hi) {
            int mid = (lo + hi) >> 1, v = inact[mid];
            if (v == i) { r = mid; break; }
            if (v < i) lo = mid + 1; else hi = mid - 1;
        }
    }
    flags[i] = f;
    rank[i] = r;
}

// ---------------------------------------------------------------------------
// K3: Rt16 (bf16, = R^T) -> R16 (bf16, transposed). 64x64 tiles via LDS.
// ---------------------------------------------------------------------------
__global__ __launch_bounds__(256) void transcast_kernel(const bf16* __restrict__ Rt16,
                                                        bf16* __restrict__ R16) {
    __shared__ ushort tile[64][65];
    const int t = threadIdx.x;
    const int bx = blockIdx.x, by = blockIdx.y;
    const int tr = t >> 4;
    const int tc = (t & 15) * 4;
#pragma unroll
    for (int k = 0; k < 4; k++) {
        int r = tr + 16 * k;
        const ushort* src = (const ushort*)Rt16 + (size_t)(by * 64 + r) * N + bx * 64 + tc;
        ushort4 v = *(const ushort4*)src;
        tile[r][tc + 0] = v.x; tile[r][tc + 1] = v.y;
        tile[r][tc + 2] = v.z; tile[r][tc + 3] = v.w;
    }
    __syncthreads();
#pragma unroll
    for (int k = 0; k < 4; k++) {
        int r = tr + 16 * k;
        ushort4 w;
        w.x = tile[tc + 0][r];
        w.y = tile[tc + 1][r];
        w.z = tile[tc + 2][r];
        w.w = tile[tc + 3][r];
        *(ushort4*)((ushort*)R16 + (size_t)(bx * 64 + r) * N + by * 64 + tc) = w;
    }
}

// ---------------------------------------------------------------------------
// castA: fp32 A -> bf16 A16.
// ---------------------------------------------------------------------------
__global__ __launch_bounds__(256) void castA_kernel(const float* __restrict__ A,
                                                    bf16* __restrict__ A16) {
    const size_t i = ((size_t)blockIdx.x * 256 + threadIdx.x) * 4;
    float4 v = *(const float4*)(A + i);
    ushort4 o;
    o.x = f2us(v.x); o.y = f2us(v.y); o.z = f2us(v.z); o.w = f2us(v.w);
    *(ushort4*)((ushort*)A16 + i) = o;
}

// ---------------------------------------------------------------------------
// K4: scatter rows of R (bf16) to father/mother outputs (fp32).
// ---------------------------------------------------------------------------
__global__ __launch_bounds__(64) void rowgather_kernel(const bf16* __restrict__ R16,
                                                       const int* __restrict__ flags,
                                                       const int* __restrict__ rank,
                                                       float* __restrict__ father,
                                                       float* __restrict__ mother) {
    const int i = blockIdx.x;
    const int t = threadIdx.x;
    float* dst = flags[i] ? (father + (size_t)rank[i] * N) : (mother + (size_t)rank[i] * N);
    const ushort* src = (const ushort*)(R16 + (size_t)i * N);
    for (int j = t * 4; j < N; j += 64 * 4) {
        ushort4 v = *(const ushort4*)(src + j);
        float4 o;
        o.x = us2f(v.x); o.y = us2f(v.y); o.z = us2f(v.z); o.w = us2f(v.w);
        *(float4*)(dst + j) = o;
    }
}

// ---------------------------------------------------------------------------
// K6: wavelets. Block l: u = St[drp[l],:] (= row d of P_l A, since row d of R
// is frozen after step l), then apply steps 0..l: u[sel_a] = sum_i O[a][i]
// u[sel_i]. wavelet_l = u. fp32 out.
// ---------------------------------------------------------------------------
__global__ __launch_bounds__(64) void wavelet_kernel(const bf16* __restrict__ St,
                                                     const float* __restrict__ Os,
                                                     const int* __restrict__ sel,
                                                     const int* __restrict__ drp,
                                                     float* __restrict__ wout) {
    __shared__ float u[N];
    const int t = threadIdx.x;
    const int l = blockIdx.x;
    const int d = drp[l];
    const ushort* src = (const ushort*)(St + (size_t)d * N);
    for (int j = t; j < N; j += 64) u[j] = us2f(src[j]);
    __syncthreads();
    for (int m = 0; m <= l; m++) {
        float v = 0.0f;
        int wrow = 0;
        if (t < 16) {
#pragma unroll
            for (int i = 0; i < 16; i++) {
                int si = sel[m * 16 + i];
                v += Os[m * 256 + t * 16 + i] * u[si];
            }
            wrow = sel[m * 16 + t];
        }
        __syncthreads();
        if (t < 16) u[wrow] = v;
        __syncthreads();
    }
    float* dst = wout + (size_t)l * N;
    for (int j = t; j < N; j += 64) dst[j] = u[j];
}

// ---------------------------------------------------------------------------
// K8: mask/core. Reads AL16 (bf16). Writes: core rows (fp32, if active),
// masked D (fp32) to out_D, masked D16 (bf16) for the K9 GEMM.
// ---------------------------------------------------------------------------
__global__ __launch_bounds__(256) void maskcore_kernel(const bf16* __restrict__ AL16,
                                                       const int* __restrict__ flags,
                                                       const int* __restrict__ rank,
                                                       float* __restrict__ Dout,
                                                       bf16* __restrict__ D16,
                                                       float* __restrict__ core) {
    const int i = blockIdx.y;
    const int j0 = (blockIdx.x * 256 + threadIdx.x) * 4;
    const int fi = flags[i];
    const int ri = rank[i];
    ushort4 v = *(const ushort4*)((const ushort*)AL16 + (size_t)i * N + j0);
    float4 vf;
    vf.x = us2f(v.x); vf.y = us2f(v.y); vf.z = us2f(v.z); vf.w = us2f(v.w);
    if (fi) *(float4*)(core + (size_t)ri * N + j0) = vf;
    const int4 fj = *(const int4*)(flags + j0);
    bool k0 = (i == j0 + 0) || (fi && fj.x);
    bool k1 = (i == j0 + 1) || (fi && fj.y);
    bool k2 = (i == j0 + 2) || (fi && fj.z);
    bool k3 = (i == j0 + 3) || (fi && fj.w);
    float4 df;
    df.x = k0 ? vf.x : 0.0f; df.y = k1 ? vf.y : 0.0f;
    df.z = k2 ? vf.z : 0.0f; df.w = k3 ? vf.w : 0.0f;
    *(float4*)(Dout + (size_t)i * N + j0) = df;
    ushort4 dv;
    dv.x = k0 ? v.x : (ushort)0; dv.y = k1 ? v.y : (ushort)0;
    dv.z = k2 ? v.z : (ushort)0; dv.w = k3 ? v.w : (ushort)0;
    *(ushort4*)((ushort*)D16 + (size_t)i * N + j0) = dv;
}

// ---------------------------------------------------------------------------
// GEMM: C[M,N] = Amat @ Bt^T, fp32 acc, bf16 inputs, bf16 or fp32 out.
// m97 structure: 128x128 tile, BK=32, global_load_lds width 16,
// 4 waves x (4x4) mfma 16x16x32 bf16.
// ---------------------------------------------------------------------------
template <bool F32OUT>
__global__ __launch_bounds__(256) void gemm_bt_kernel(const bf16* __restrict__ Amat,
                                                      const bf16* __restrict__ Bt,
                                                      void* __restrict__ Cv) {
    __shared__ bf16 As[128 * 32];
    __shared__ bf16 Bs[128 * 32];
    const int t = threadIdx.x;
    const int lane = t & 63;
    const int wave = t >> 6;
    const int rowBase = blockIdx.y * 128;
    const int colBase = blockIdx.x * 128;
    const int mq = (wave >> 1) * 64;
    const int nq = (wave & 1) * 64;

    floatx4 acc[4][4] = {};

    const int lrow = lane >> 2;        // 0..15: row within 16-row chunk
    const int lke = (lane & 3) * 8;    // element offset within 32-wide k slab
    const int frow = lane & 15;
    const int fkb = (lane >> 4) * 16;  // byte offset of 8-elem k group

    for (int k0 = 0; k0 < N; k0 += 32) {
#pragma unroll
        for (int c = 0; c < 2; c++) {
            const int chunk = wave * 2 + c;
            const int grow = chunk * 16 + lrow;
            const bf16* ga = Amat + (size_t)(rowBase + grow) * N + k0 + lke;
            const bf16* gb = Bt + (size_t)(colBase + grow) * N + k0 + lke;
            char* lA = (char*)As + chunk * 1024;
            char* lB = (char*)Bs + chunk * 1024;
            __builtin_amdgcn_global_load_lds((const __attribute__((address_space(1))) void*)ga,
                                             (__attribute__((address_space(3))) void*)lA, 16, 0, 0);
            __builtin_amdgcn_global_load_lds((const __attribute__((address_space(1))) void*)gb,
                                             (__attribute__((address_space(3))) void*)lB, 16, 0, 0);
        }
        __syncthreads();

        short8 af[4], bfv[4];
#pragma unroll
        for (int mi = 0; mi < 4; mi++) {
            const char* p = (const char*)As + (mq + mi * 16 + frow) * 64 + fkb;
            af[mi] = *(const short8*)p;
        }
#pragma unroll
        for (int ni = 0; ni < 4; ni++) {
            const char* p = (const char*)Bs + (nq + ni * 16 + frow) * 64 + fkb;
            bfv[ni] = *(const short8*)p;
        }
#pragma unroll
        for (int mi = 0; mi < 4; mi++)
#pragma unroll
            for (int ni = 0; ni < 4; ni++)
                acc[mi][ni] = __builtin_amdgcn_mfma_f32_16x16x32_bf16(af[mi], bfv[ni], acc[mi][ni], 0, 0, 0);
        __syncthreads();
    }

    const int crow = (lane >> 4) * 4;
    const int ccol = lane & 15;
#pragma unroll
    for (int mi = 0; mi < 4; mi++)
#pragma unroll
        for (int ni = 0; ni < 4; ni++)
#pragma unroll
            for (int r = 0; r < 4; r++) {
                const int gr = rowBase + mq + mi * 16 + crow + r;
                const int gc = colBase + nq + ni * 16 + ccol;
                if (F32OUT) ((float*)Cv)[(size_t)gr * N + gc] = acc[mi][ni][r];
                else ((bf16*)Cv)[(size_t)gr * N + gc] = f2bf(acc[mi][ni][r]);
            }
}

// ---------------------------------------------------------------------------
// Dtypes per the reference: A, Os fp32; sel/drp/act/inact int32; outputs fp32.
// Internal compute bf16 MFMA with fp32 accumulate (error << 2% threshold).
//
// Workspace (96 MB): [0,32)MB A16 -> AL16 -> Tt16 (time-shared);
//                    [32,64)MB R16; [64,96)MB Rt16.
// Output-region scratch: St16 in A_rec[0,32MB); D16 in A_rec[32,64MB) bytes
// (both dead before K10 overwrites); flags/rank in wavelets region (dead
// before K6 overwrites).
// ---------------------------------------------------------------------------
extern "C" void kernel_launch(void* const* d_in, const int* in_sizes, int n_in,
                              void* d_out, int out_size, void* d_ws, size_t ws_size,
                              hipStream_t stream) {
    const float* A = (const float*)d_in[0];
    const float* Os = (const float*)d_in[1];
    const int* sel = (const int*)d_in[2];
    const int* drp = (const int*)d_in[3];
    const int* act = (const int*)d_in[4];
    const int* inact = (const int*)d_in[5];

    float* out = (float*)d_out;
    float* out_Arec = out;                          // 4096*4096
    float* out_D    = out + 16777216;               // 4096*4096
    float* out_wav  = out + 33554432;               // 128*4096
    float* out_core = out + 34078720;               // 3968*4096
    float* out_moth = out + 50331648;               // 128*4096
    float* out_fath = out + 50855936;               // 3968*4096

    char* ws = (char*)d_ws;
    const size_t MB = 1024 * 1024;
    bf16* A16  = (bf16*)(ws + 0);             // dead after K5
    bf16* AL16 = (bf16*)(ws + 0);             // written K7, dead after K8
    bf16* Tt16 = (bf16*)(ws + 0);             // written K9, dead after K10
    bf16* R16  = (bf16*)(ws + 32 * MB);
    bf16* Rt16 = (bf16*)(ws + 64 * MB);
    bf16* St16 = (bf16*)out_Arec;                   // A_rec bytes [0,32MB)
    bf16* D16  = (bf16*)(out_Arec + 8388608);       // A_rec bytes [32,64MB)
    int* flags = (int*)out_wav;                     // dead before K6
    int* rank  = flags + N;

    // K1: sequential right-scan -> Rt16 (= R^T, bf16)
    rscan_kernel<<<dim3(N / 4), dim3(64), 0, stream>>>(Os, sel, Rt16);
    // K2: active flags + ranks (scratch in wavelets region)
    prep_kernel<<<dim3(16), dim3(256), 0, stream>>>(act, inact, flags, rank);
    // K3: R16 = transpose(Rt16)
    transcast_kernel<<<dim3(64, 64), dim3(256), 0, stream>>>(Rt16, R16);
    // K4: father/mother rows of R (fp32 out)
    rowgather_kernel<<<dim3(N), dim3(64), 0, stream>>>(R16, flags, rank, out_fath, out_moth);
    // castA: A fp32 -> bf16
    castA_kernel<<<dim3(16384), dim3(256), 0, stream>>>(A, A16);
    // K5: St = R @ A (A symmetric) -> A_rec region scratch
    gemm_bt_kernel<false><<<dim3(32, 32), dim3(256), 0, stream>>>(R16, A16, St16);
    // K7: A_L = R @ St^T -> ws slot 0 (A16 dead)
    gemm_bt_kernel<false><<<dim3(32, 32), dim3(256), 0, stream>>>(R16, St16, AL16);
    // K8: core rows (fp32) + masked D (fp32) + masked D16 (bf16)
    maskcore_kernel<<<dim3(4, N), dim3(256), 0, stream>>>(AL16, flags, rank, out_D, D16, out_core);
    // K6: wavelets from St rows (fp32 out; overwrites flags/rank — dead)
    wavelet_kernel<<<dim3(LSTEPS), dim3(64), 0, stream>>>(St16, Os, sel, drp, out_wav);
    // K9: Tt = R^T @ D (D symmetric to bf16 noise) -> ws slot 0 (AL16 dead)
    gemm_bt_kernel<false><<<dim3(32, 32), dim3(256), 0, stream>>>(Rt16, D16, Tt16);
    // K10: A_rec = Tt @ Rt^T = R^T D R -> fp32 out (St16/D16 scratch dead)
    gemm_bt_kernel<true><<<dim3(32, 32), dim3(256), 0, stream>>>(Tt16, Rt16, out_Arec);
}